// Round 4
// baseline (215.722 us; speedup 1.0000x reference)
//
#include <hip/hip_runtime.h>
#include <math.h>

#define NPOS 13824   // 24*24*24
#define CDIM 64
#define BTCH 2
#define LOG2E 1.4426950408889634f
#define QSCALE (0.125f * LOG2E)

__device__ __forceinline__ unsigned int f2bf1(float f) {   // RNE float->bf16
  unsigned int u = __float_as_uint(f);
  return (u + 0x7FFFu + ((u >> 16) & 1u)) >> 16;
}

// ---------------------------------------------------------------------------
// Kernel 1: Q/K/V/GX projections (1x1x1 convs), outputs in (B,N,C) layout,
// plus x-transpose XT (N,C). Q is pre-scaled by 0.125*log2(e).
// Zeroes pool + ticket counter.
// ---------------------------------------------------------------------------
__global__ __launch_bounds__(256) void qkvg_kernel(
    const float* __restrict__ x,
    const float* __restrict__ Wq, const float* __restrict__ bq,
    const float* __restrict__ Wk, const float* __restrict__ bk,
    const float* __restrict__ Wv, const float* __restrict__ bv,
    const float* __restrict__ Wg,
    float* __restrict__ Qb, float* __restrict__ Kb, float* __restrict__ Vb,
    float* __restrict__ GXb, float* __restrict__ XT, float* __restrict__ pool)
{
  __shared__ __align__(16) float wqt[64*68];
  __shared__ __align__(16) float wkt[64*68];
  __shared__ __align__(16) float wvt[64*68];
  __shared__ __align__(16) float wgt[64*68];
  const int t  = threadIdx.x;
  const int bi = blockIdx.x;
  const int b  = bi / 216;
  const int n0 = (bi - b*216) * 64;
  if (bi == 0 && t < 132) pool[t] = 0.0f;   // pool[128] + counter + pad

  #pragma unroll
  for (int k = 0; k < 16; ++k) {
    int idx = t + k*256;                 // 0..4095
    int lo = idx & 63, hi = idx >> 6;
    wqt[lo*68 + hi] = Wq[idx] * QSCALE;  // [c_in][c_out], Q pre-scaled
    wkt[lo*68 + hi] = Wk[idx];
    wvt[lo*68 + hi] = Wv[idx];
    wgt[lo*68 + hi] = Wg[hi*128 + lo];   // first 64 columns of Wg
  }
  __syncthreads();

  const int c0  = (t & 15) * 4;          // 4 output channels
  const int nn0 = (t >> 4) * 4;          // 4 positions
  const float* xbase = x + (size_t)(b*64)*NPOS + n0 + nn0;
  float aq[4][4] = {}; float ak[4][4] = {}; float av[4][4] = {}; float ag[4][4] = {};
  #pragma unroll 4
  for (int cp = 0; cp < 64; ++cp) {
    const float4 xv4 = *(const float4*)(xbase + (size_t)cp*NPOS);
    const float4 q4  = *(const float4*)&wqt[cp*68 + c0];
    const float4 k4  = *(const float4*)&wkt[cp*68 + c0];
    const float4 v4  = *(const float4*)&wvt[cp*68 + c0];
    const float4 g4  = *(const float4*)&wgt[cp*68 + c0];
    const float xa[4] = {xv4.x, xv4.y, xv4.z, xv4.w};
    const float qa[4] = {q4.x, q4.y, q4.z, q4.w};
    const float ka[4] = {k4.x, k4.y, k4.z, k4.w};
    const float va[4] = {v4.x, v4.y, v4.z, v4.w};
    const float ga[4] = {g4.x, g4.y, g4.z, g4.w};
    #pragma unroll
    for (int ci = 0; ci < 4; ++ci)
      #pragma unroll
      for (int ni = 0; ni < 4; ++ni) {
        aq[ci][ni] = fmaf(qa[ci], xa[ni], aq[ci][ni]);
        ak[ci][ni] = fmaf(ka[ci], xa[ni], ak[ci][ni]);
        av[ci][ni] = fmaf(va[ci], xa[ni], av[ci][ni]);
        ag[ci][ni] = fmaf(ga[ci], xa[ni], ag[ci][ni]);
      }
  }
  const float4 bq4 = *(const float4*)&bq[c0];
  const float4 bk4 = *(const float4*)&bk[c0];
  const float4 bv4 = *(const float4*)&bv[c0];
  #pragma unroll
  for (int ni = 0; ni < 4; ++ni) {
    const int p = b*NPOS + n0 + nn0 + ni;   // (N,C) layout: [p*64 + c]
    float4 o;
    o = make_float4(fmaf(bq4.x,QSCALE,aq[0][ni]), fmaf(bq4.y,QSCALE,aq[1][ni]),
                    fmaf(bq4.z,QSCALE,aq[2][ni]), fmaf(bq4.w,QSCALE,aq[3][ni]));
    *(float4*)&Qb[p*64 + c0] = o;
    o = make_float4(ak[0][ni]+bk4.x, ak[1][ni]+bk4.y, ak[2][ni]+bk4.z, ak[3][ni]+bk4.w);
    *(float4*)&Kb[p*64 + c0] = o;
    o = make_float4(av[0][ni]+bv4.x, av[1][ni]+bv4.y, av[2][ni]+bv4.z, av[3][ni]+bv4.w);
    *(float4*)&Vb[p*64 + c0] = o;
    o = make_float4(ag[0][ni], ag[1][ni], ag[2][ni], ag[3][ni]); // bg added in attn
    *(float4*)&GXb[p*64 + c0] = o;
  }
  float4 xr[4];
  #pragma unroll
  for (int e = 0; e < 4; ++e)
    xr[e] = *(const float4*)(x + (size_t)(b*64 + c0 + e)*NPOS + n0 + nn0);
  const float xre[4][4] = {{xr[0].x,xr[0].y,xr[0].z,xr[0].w},
                           {xr[1].x,xr[1].y,xr[1].z,xr[1].w},
                           {xr[2].x,xr[2].y,xr[2].z,xr[2].w},
                           {xr[3].x,xr[3].y,xr[3].z,xr[3].w}};
  #pragma unroll
  for (int ni = 0; ni < 4; ++ni) {
    const int p = b*NPOS + n0 + nn0 + ni;
    *(float4*)&XT[p*64 + c0] = make_float4(xre[0][ni], xre[1][ni], xre[2][ni], xre[3][ni]);
  }
}

// ---------------------------------------------------------------------------
// Kernel 2: fused tiled attention. 3x3x3 tile per block; 5x5x5 K/V halo in
// LDS as packed bf16 pairs (hi=K, lo=V) -> 31.25 KB, 4 blocks/CU.
// Gate weights in VGPRs; direct scattered stores; pool + GRU tail fused.
// ---------------------------------------------------------------------------
__global__ __launch_bounds__(256, 4) void attn_fused(
    const float* __restrict__ Qb,
    const float* __restrict__ Kb, const float* __restrict__ Vb,
    const float* __restrict__ GXb, const float* __restrict__ XT,
    const float* __restrict__ bk, const float* __restrict__ bv,
    const float* __restrict__ memk, const float* __restrict__ memv,
    const float* __restrict__ Wg, const float* __restrict__ bg,
    float* __restrict__ out, float* __restrict__ pool, int* __restrict__ cnt,
    const float* __restrict__ prev,
    const float* __restrict__ W_ih, const float* __restrict__ W_hh,
    const float* __restrict__ b_ih, const float* __restrict__ b_hh,
    float* __restrict__ outmem)
{
  __shared__ __align__(16) unsigned int kvbuf[8000]; // 125 slots x 64 ch, bf16 K|V
  __shared__ __align__(16) float als[256];
  __shared__ int flag;
  const int t = threadIdx.x;
  const int c = t & 63;
  const int w = t >> 6;
  if (t == 0) flag = 0;

  // stage Wg[:,64:] into padded-65 transpose (overlay on kvbuf), to registers
  {
    float* wgt2 = (float*)kvbuf;
    #pragma unroll
    for (int k = 0; k < 16; ++k) {
      int u = t + k*256;
      int cp = u >> 6, j = u & 63;
      wgt2[j*65 + cp] = Wg[cp*128 + 64 + j];
    }
  }
  __syncthreads();
  float wg2reg[64];
  {
    const float* wgt2 = (const float*)kvbuf;
    #pragma unroll
    for (int j = 0; j < 64; ++j) wg2reg[j] = wgt2[j*65 + c];
  }
  float mk[5], mv[5];
  #pragma unroll
  for (int m = 0; m < 5; ++m) { mk[m] = memk[c*5 + m]; mv[m] = memv[c*5 + m]; }
  const float bg_c = bg[c];
  __syncthreads();

  const int bi = blockIdx.x;
  const int b  = bi >> 9;                 // 512 tiles (8x8x8) per batch
  const int tb = bi & 511;
  const int h0 = (tb >> 6) * 3;
  const int d0 = ((tb >> 3) & 7) * 3;
  const int w0 = (tb & 7) * 3;
  const int bN = b * NPOS;

  // stage 5x5x5 packed K/V halo (OOB -> bias)
  for (int u = t; u < 125*16; u += 256) {
    int pos = u >> 4, q4 = u & 15;
    int ph = pos / 25, pr = pos - ph*25;
    int pd = pr / 5,  pw = pr - pd*5;
    int hh = h0 - 1 + ph, dd = d0 - 1 + pd, ww = w0 - 1 + pw;
    bool inb = ((unsigned)hh < 24u) && ((unsigned)dd < 24u) && ((unsigned)ww < 24u);
    float4 kf, vf;
    if (inb) {
      const size_t off = ((size_t)(bN + hh*576 + dd*24 + ww))*64 + q4*4;
      kf = *(const float4*)(Kb + off);
      vf = *(const float4*)(Vb + off);
    } else {
      kf = ((const float4*)bk)[q4];
      vf = ((const float4*)bv)[q4];
    }
    uint4 pk;
    pk.x = (f2bf1(kf.x) << 16) | f2bf1(vf.x);
    pk.y = (f2bf1(kf.y) << 16) | f2bf1(vf.y);
    pk.z = (f2bf1(kf.z) << 16) | f2bf1(vf.z);
    pk.w = (f2bf1(kf.w) << 16) | f2bf1(vf.w);
    *(uint4*)&kvbuf[pos*64 + q4*4] = pk;
  }
  __syncthreads();

  float pacc = 0.0f;
  for (int li = w; li < 27; li += 4) {
    const int lh = li / 9, lr = li - lh*9;
    const int ld = lr / 3, lw = lr - ld*3;
    const int n  = (h0+lh)*576 + (d0+ld)*24 + (w0+lw);
    const int p  = bN + n;
    const unsigned int* kvp = &kvbuf[(lh*25 + ld*5 + lw)*64 + c];

    const float q2 = Qb[p*64 + c];        // pre-scaled by 0.125*log2e

    // pass 1: running max over 32 logits (4 parallel accumulators)
    float mx0 = q2*mk[0], mx1 = q2*mk[1], mx2 = q2*mk[2], mx3 = q2*mk[3];
    mx0 = fmaxf(mx0, q2*mk[4]);
    #pragma unroll
    for (int i = 0; i < 3; ++i)
      #pragma unroll
      for (int j = 0; j < 3; ++j)
        #pragma unroll
        for (int l = 0; l < 3; ++l) {
          int s4 = i*9 + j*3 + l;
          float kf = __uint_as_float(kvp[(i*25 + j*5 + l)*64] & 0xFFFF0000u);
          float lv = q2 * kf;
          if ((s4 & 3) == 0) mx0 = fmaxf(mx0, lv);
          else if ((s4 & 3) == 1) mx1 = fmaxf(mx1, lv);
          else if ((s4 & 3) == 2) mx2 = fmaxf(mx2, lv);
          else mx3 = fmaxf(mx3, lv);
        }
    const float maxv = fmaxf(fmaxf(mx0, mx1), fmaxf(mx2, mx3));

    // pass 2: exp-sum + weighted values (recompute logits, extract V)
    float s0 = 0.f, s1 = 0.f, o0 = 0.f, o1 = 0.f;
    #pragma unroll
    for (int m = 0; m < 5; ++m) {
      float pf = __builtin_amdgcn_exp2f(fmaf(q2, mk[m], -maxv));
      if (m & 1) { s1 += pf; o1 = fmaf(pf, mv[m], o1); }
      else       { s0 += pf; o0 = fmaf(pf, mv[m], o0); }
    }
    #pragma unroll
    for (int i = 0; i < 3; ++i)
      #pragma unroll
      for (int j = 0; j < 3; ++j)
        #pragma unroll
        for (int l = 0; l < 3; ++l) {
          int s4 = i*9 + j*3 + l;
          unsigned int kv = kvp[(i*25 + j*5 + l)*64];
          float kf = __uint_as_float(kv & 0xFFFF0000u);
          float vf = __uint_as_float(kv << 16);
          float pf = __builtin_amdgcn_exp2f(fmaf(q2, kf, -maxv));
          if (s4 & 1) { s1 += pf; o1 = fmaf(pf, vf, o1); }
          else        { s0 += pf; o0 = fmaf(pf, vf, o0); }
        }
    const float att = (o0 + o1) * __builtin_amdgcn_rcpf(s0 + s1);

    als[w*64 + c] = att;                  // wave-local broadcast buffer
    float g0 = GXb[p*64 + c] + bg_c, g1 = 0.f, g2 = 0.f, g3 = 0.f;
    #pragma unroll
    for (int j4 = 0; j4 < 16; ++j4) {
      const float4 a4 = *(const float4*)&als[w*64 + j4*4];  // same-addr broadcast
      g0 = fmaf(wg2reg[j4*4+0], a4.x, g0);
      g1 = fmaf(wg2reg[j4*4+1], a4.y, g1);
      g2 = fmaf(wg2reg[j4*4+2], a4.z, g2);
      g3 = fmaf(wg2reg[j4*4+3], a4.w, g3);
    }
    const float gl   = (g0 + g1) + (g2 + g3);
    const float gate = __builtin_amdgcn_rcpf(1.0f + __builtin_amdgcn_exp2f(-LOG2E * gl));
    const float xv   = XT[p*64 + c];
    const float fin  = fmaf(gate, att - xv, xv);
    out[(size_t)(b*64 + c)*NPOS + n] = fin;   // scatter; L2 gathers lines
    pacc += fin;
  }

  // pool reduce: 4 waves -> 64 lanes -> 64 device atomics
  als[t] = pacc;
  __syncthreads();
  if (t < 64) {
    float s = als[t] + als[64 + t] + als[128 + t] + als[192 + t];
    atomicAdd(&pool[b*64 + t], s);
  }
  if (t == 0) {
    __threadfence();
    if (atomicAdd(cnt, 1) == (int)gridDim.x - 1) flag = 1;
  }
  __syncthreads();

  // ---- last block: GRU cell on pooled mean (overlay kvbuf) ----
  if (flag) {
    float* mu = (float*)kvbuf; float* gi = mu + 128; float* gh = mu + 512;
    if (t < 128)
      mu[t] = __hip_atomic_load(&pool[t], __ATOMIC_RELAXED,
                                __HIP_MEMORY_SCOPE_AGENT) * (1.0f / (float)NPOS);
    __syncthreads();
    for (int r = t; r < 384; r += 256) {
      const int b2 = r / 192, j = r - b2*192;
      const float4* wi4 = (const float4*)(W_ih + (size_t)j*64);
      const float4* wh4 = (const float4*)(W_hh + (size_t)j*64);
      const float4* mu4 = (const float4*)(mu + b2*64);
      const float4* pv4 = (const float4*)(prev + b2*64);
      float sgi = b_ih[j], sgh = b_hh[j];
      #pragma unroll
      for (int k = 0; k < 16; ++k) {
        float4 wv = wi4[k], m4 = mu4[k];
        sgi = fmaf(wv.x, m4.x, sgi); sgi = fmaf(wv.y, m4.y, sgi);
        sgi = fmaf(wv.z, m4.z, sgi); sgi = fmaf(wv.w, m4.w, sgi);
        float4 hv = wh4[k], p4 = pv4[k];
        sgh = fmaf(hv.x, p4.x, sgh); sgh = fmaf(hv.y, p4.y, sgh);
        sgh = fmaf(hv.z, p4.z, sgh); sgh = fmaf(hv.w, p4.w, sgh);
      }
      gi[r] = sgi; gh[r] = sgh;
    }
    __syncthreads();
    if (t < 128) {
      const int b2 = t >> 6, cc = t & 63;
      float ir = gi[b2*192 + cc],       hr = gh[b2*192 + cc];
      float iz = gi[b2*192 + 64 + cc],  hz = gh[b2*192 + 64 + cc];
      float ii = gi[b2*192 + 128 + cc], hn = gh[b2*192 + 128 + cc];
      float rr = 1.0f / (1.0f + __builtin_amdgcn_exp2f(-LOG2E * (ir + hr)));
      float zz = 1.0f / (1.0f + __builtin_amdgcn_exp2f(-LOG2E * (iz + hz)));
      float ng = tanhf(ii + rr * hn);
      outmem[t] = (1.0f - zz) * ng + zz * prev[t];
    }
  }
}

// ---------------------------------------------------------------------------
extern "C" void kernel_launch(void* const* d_in, const int* in_sizes, int n_in,
                              void* d_out, int out_size, void* d_ws, size_t ws_size,
                              hipStream_t stream) {
  const float* x    = (const float*)d_in[0];
  const float* prev = (const float*)d_in[1];
  const float* Wq   = (const float*)d_in[2];
  const float* bq   = (const float*)d_in[3];
  const float* Wk   = (const float*)d_in[4];
  const float* bk   = (const float*)d_in[5];
  const float* Wv   = (const float*)d_in[6];
  const float* bv   = (const float*)d_in[7];
  const float* memk = (const float*)d_in[8];
  const float* memv = (const float*)d_in[9];
  const float* Wg   = (const float*)d_in[10];
  const float* bg   = (const float*)d_in[11];
  const float* W_ih = (const float*)d_in[12];
  const float* W_hh = (const float*)d_in[13];
  const float* b_ih = (const float*)d_in[14];
  const float* b_hh = (const float*)d_in[15];

  float* out    = (float*)d_out;                 // (B,C,H,D,W)
  float* outmem = out + (size_t)BTCH*CDIM*NPOS;  // (B,C)

  const size_t SZ = (size_t)BTCH*NPOS*CDIM;      // 1769472
  float* wsf  = (float*)d_ws;
  float* Qb   = wsf;
  float* Kb   = wsf + SZ;
  float* Vb   = wsf + 2*SZ;
  float* GXb  = wsf + 3*SZ;
  float* XT   = wsf + 4*SZ;
  float* pool = wsf + 5*SZ;                      // 128 floats + counter
  int*   cnt  = (int*)(pool + 128);

  qkvg_kernel<<<BTCH*216, 256, 0, stream>>>(x, Wq, bq, Wk, bk, Wv, bv, Wg,
                                            Qb, Kb, Vb, GXb, XT, pool);
  attn_fused<<<BTCH*512, 256, 0, stream>>>(Qb, Kb, Vb, GXb, XT,
                                           bk, bv, memk, memv, Wg, bg,
                                           out, pool, cnt,
                                           prev, W_ih, W_hh, b_ih, b_hh, outmem);
}

// Round 5
// 174.132 us; speedup vs baseline: 1.2388x; 1.2388x over previous
//
#include <hip/hip_runtime.h>
#include <math.h>

#define NPOS 13824   // 24*24*24
#define CDIM 64
#define BTCH 2
#define LOG2E 1.4426950408889634f
#define QSCALE (0.125f * LOG2E)

__device__ __forceinline__ unsigned int f2bf1(float f) {   // RNE float->bf16
  unsigned int u = __float_as_uint(f);
  return (u + 0x7FFFu + ((u >> 16) & 1u)) >> 16;
}

// ---------------------------------------------------------------------------
// Kernel 1: Q/K/V/GX projections (1x1x1 convs), outputs in (B,N,C) layout,
// plus x-transpose XT (N,C). Q pre-scaled by 0.125*log2(e). Zeroes pool.
// ---------------------------------------------------------------------------
__global__ __launch_bounds__(256) void qkvg_kernel(
    const float* __restrict__ x,
    const float* __restrict__ Wq, const float* __restrict__ bq,
    const float* __restrict__ Wk, const float* __restrict__ bk,
    const float* __restrict__ Wv, const float* __restrict__ bv,
    const float* __restrict__ Wg,
    float* __restrict__ Qb, float* __restrict__ Kb, float* __restrict__ Vb,
    float* __restrict__ GXb, float* __restrict__ XT, float* __restrict__ pool)
{
  __shared__ __align__(16) float wqt[64*68];
  __shared__ __align__(16) float wkt[64*68];
  __shared__ __align__(16) float wvt[64*68];
  __shared__ __align__(16) float wgt[64*68];
  const int t  = threadIdx.x;
  const int bi = blockIdx.x;
  const int b  = bi / 216;
  const int n0 = (bi - b*216) * 64;
  if (bi == 0 && t < 128) pool[t] = 0.0f;

  #pragma unroll
  for (int k = 0; k < 16; ++k) {
    int idx = t + k*256;                 // 0..4095
    int lo = idx & 63, hi = idx >> 6;
    wqt[lo*68 + hi] = Wq[idx] * QSCALE;  // [c_in][c_out], Q pre-scaled
    wkt[lo*68 + hi] = Wk[idx];
    wvt[lo*68 + hi] = Wv[idx];
    wgt[lo*68 + hi] = Wg[hi*128 + lo];   // first 64 columns of Wg
  }
  __syncthreads();

  const int c0  = (t & 15) * 4;          // 4 output channels
  const int nn0 = (t >> 4) * 4;          // 4 positions
  const float* xbase = x + (size_t)(b*64)*NPOS + n0 + nn0;
  float aq[4][4] = {}; float ak[4][4] = {}; float av[4][4] = {}; float ag[4][4] = {};
  #pragma unroll 4
  for (int cp = 0; cp < 64; ++cp) {
    const float4 xv4 = *(const float4*)(xbase + (size_t)cp*NPOS);
    const float4 q4  = *(const float4*)&wqt[cp*68 + c0];
    const float4 k4  = *(const float4*)&wkt[cp*68 + c0];
    const float4 v4  = *(const float4*)&wvt[cp*68 + c0];
    const float4 g4  = *(const float4*)&wgt[cp*68 + c0];
    const float xa[4] = {xv4.x, xv4.y, xv4.z, xv4.w};
    const float qa[4] = {q4.x, q4.y, q4.z, q4.w};
    const float ka[4] = {k4.x, k4.y, k4.z, k4.w};
    const float va[4] = {v4.x, v4.y, v4.z, v4.w};
    const float ga[4] = {g4.x, g4.y, g4.z, g4.w};
    #pragma unroll
    for (int ci = 0; ci < 4; ++ci)
      #pragma unroll
      for (int ni = 0; ni < 4; ++ni) {
        aq[ci][ni] = fmaf(qa[ci], xa[ni], aq[ci][ni]);
        ak[ci][ni] = fmaf(ka[ci], xa[ni], ak[ci][ni]);
        av[ci][ni] = fmaf(va[ci], xa[ni], av[ci][ni]);
        ag[ci][ni] = fmaf(ga[ci], xa[ni], ag[ci][ni]);
      }
  }
  const float4 bq4 = *(const float4*)&bq[c0];
  const float4 bk4 = *(const float4*)&bk[c0];
  const float4 bv4 = *(const float4*)&bv[c0];
  #pragma unroll
  for (int ni = 0; ni < 4; ++ni) {
    const int p = b*NPOS + n0 + nn0 + ni;   // (N,C) layout: [p*64 + c]
    float4 o;
    o = make_float4(fmaf(bq4.x,QSCALE,aq[0][ni]), fmaf(bq4.y,QSCALE,aq[1][ni]),
                    fmaf(bq4.z,QSCALE,aq[2][ni]), fmaf(bq4.w,QSCALE,aq[3][ni]));
    *(float4*)&Qb[p*64 + c0] = o;
    o = make_float4(ak[0][ni]+bk4.x, ak[1][ni]+bk4.y, ak[2][ni]+bk4.z, ak[3][ni]+bk4.w);
    *(float4*)&Kb[p*64 + c0] = o;
    o = make_float4(av[0][ni]+bv4.x, av[1][ni]+bv4.y, av[2][ni]+bv4.z, av[3][ni]+bv4.w);
    *(float4*)&Vb[p*64 + c0] = o;
    o = make_float4(ag[0][ni], ag[1][ni], ag[2][ni], ag[3][ni]); // bg added in attn
    *(float4*)&GXb[p*64 + c0] = o;
  }
  float4 xr[4];
  #pragma unroll
  for (int e = 0; e < 4; ++e)
    xr[e] = *(const float4*)(x + (size_t)(b*64 + c0 + e)*NPOS + n0 + nn0);
  const float xre[4][4] = {{xr[0].x,xr[0].y,xr[0].z,xr[0].w},
                           {xr[1].x,xr[1].y,xr[1].z,xr[1].w},
                           {xr[2].x,xr[2].y,xr[2].z,xr[2].w},
                           {xr[3].x,xr[3].y,xr[3].z,xr[3].w}};
  #pragma unroll
  for (int ni = 0; ni < 4; ++ni) {
    const int p = b*NPOS + n0 + nn0 + ni;
    *(float4*)&XT[p*64 + c0] = make_float4(xre[0][ni], xre[1][ni], xre[2][ni], xre[3][ni]);
  }
}

// ---------------------------------------------------------------------------
// Kernel 2: tiled attention. 3x3x3 tile per block; 5x5x5 K/V halo in LDS as
// packed bf16 pairs (hi=K, lo=V) -> 31.25 KB, 4 blocks/CU. Gate weights in
// VGPRs. Writes COALESCED (N,C) into QOT (aliases Qb — each slot read-then-
// written by the same lane). Pool partials via 64 atomics/block.
// ---------------------------------------------------------------------------
__global__ __launch_bounds__(256, 4) void attn_kernel(
    float* __restrict__ QOT,             // in: Q (N,C, pre-scaled); out: fin
    const float* __restrict__ Kb, const float* __restrict__ Vb,
    const float* __restrict__ GXb, const float* __restrict__ XT,
    const float* __restrict__ bk, const float* __restrict__ bv,
    const float* __restrict__ memk, const float* __restrict__ memv,
    const float* __restrict__ Wg, const float* __restrict__ bg,
    float* __restrict__ pool)
{
  __shared__ __align__(16) unsigned int kvbuf[8000]; // 125 slots x 64 ch, bf16 K|V
  __shared__ __align__(16) float als[256];
  const int t = threadIdx.x;
  const int c = t & 63;
  const int w = t >> 6;

  // stage Wg[:,64:] into padded-65 transpose (overlay on kvbuf), to registers
  {
    float* wgt2 = (float*)kvbuf;
    #pragma unroll
    for (int k = 0; k < 16; ++k) {
      int u = t + k*256;
      int cp = u >> 6, j = u & 63;
      wgt2[j*65 + cp] = Wg[cp*128 + 64 + j];
    }
  }
  __syncthreads();
  float wg2reg[64];
  {
    const float* wgt2 = (const float*)kvbuf;
    #pragma unroll
    for (int j = 0; j < 64; ++j) wg2reg[j] = wgt2[j*65 + c];
  }
  float mk[5], mv[5];
  #pragma unroll
  for (int m = 0; m < 5; ++m) { mk[m] = memk[c*5 + m]; mv[m] = memv[c*5 + m]; }
  const float bg_c = bg[c];
  __syncthreads();

  const int bi = blockIdx.x;
  const int b  = bi >> 9;                 // 512 tiles (8x8x8) per batch
  const int tb = bi & 511;
  const int h0 = (tb >> 6) * 3;
  const int d0 = ((tb >> 3) & 7) * 3;
  const int w0 = (tb & 7) * 3;
  const int bN = b * NPOS;

  // stage 5x5x5 packed K/V halo (OOB -> bias)
  for (int u = t; u < 125*16; u += 256) {
    int pos = u >> 4, q4 = u & 15;
    int ph = pos / 25, pr = pos - ph*25;
    int pd = pr / 5,  pw = pr - pd*5;
    int hh = h0 - 1 + ph, dd = d0 - 1 + pd, ww = w0 - 1 + pw;
    bool inb = ((unsigned)hh < 24u) && ((unsigned)dd < 24u) && ((unsigned)ww < 24u);
    float4 kf, vf;
    if (inb) {
      const size_t off = ((size_t)(bN + hh*576 + dd*24 + ww))*64 + q4*4;
      kf = *(const float4*)(Kb + off);
      vf = *(const float4*)(Vb + off);
    } else {
      kf = ((const float4*)bk)[q4];
      vf = ((const float4*)bv)[q4];
    }
    uint4 pk;
    pk.x = (f2bf1(kf.x) << 16) | f2bf1(vf.x);
    pk.y = (f2bf1(kf.y) << 16) | f2bf1(vf.y);
    pk.z = (f2bf1(kf.z) << 16) | f2bf1(vf.z);
    pk.w = (f2bf1(kf.w) << 16) | f2bf1(vf.w);
    *(uint4*)&kvbuf[pos*64 + q4*4] = pk;
  }
  __syncthreads();

  float pacc = 0.0f;
  for (int li = w; li < 27; li += 4) {
    const int lh = li / 9, lr = li - lh*9;
    const int ld = lr / 3, lw = lr - ld*3;
    const int p  = bN + (h0+lh)*576 + (d0+ld)*24 + (w0+lw);
    const unsigned int* kvp = &kvbuf[(lh*25 + ld*5 + lw)*64 + c];

    const float q2 = QOT[p*64 + c];       // pre-scaled by 0.125*log2e

    // pass 1: running max over 32 logits (4 parallel accumulators)
    float mx0 = q2*mk[0], mx1 = q2*mk[1], mx2 = q2*mk[2], mx3 = q2*mk[3];
    mx0 = fmaxf(mx0, q2*mk[4]);
    #pragma unroll
    for (int i = 0; i < 3; ++i)
      #pragma unroll
      for (int j = 0; j < 3; ++j)
        #pragma unroll
        for (int l = 0; l < 3; ++l) {
          int s4 = i*9 + j*3 + l;
          float kf = __uint_as_float(kvp[(i*25 + j*5 + l)*64] & 0xFFFF0000u);
          float lv = q2 * kf;
          if ((s4 & 3) == 0) mx0 = fmaxf(mx0, lv);
          else if ((s4 & 3) == 1) mx1 = fmaxf(mx1, lv);
          else if ((s4 & 3) == 2) mx2 = fmaxf(mx2, lv);
          else mx3 = fmaxf(mx3, lv);
        }
    const float maxv = fmaxf(fmaxf(mx0, mx1), fmaxf(mx2, mx3));

    // pass 2: exp-sum + weighted values (recompute logits, extract V)
    float s0 = 0.f, s1 = 0.f, o0 = 0.f, o1 = 0.f;
    #pragma unroll
    for (int m = 0; m < 5; ++m) {
      float pf = __builtin_amdgcn_exp2f(fmaf(q2, mk[m], -maxv));
      if (m & 1) { s1 += pf; o1 = fmaf(pf, mv[m], o1); }
      else       { s0 += pf; o0 = fmaf(pf, mv[m], o0); }
    }
    #pragma unroll
    for (int i = 0; i < 3; ++i)
      #pragma unroll
      for (int j = 0; j < 3; ++j)
        #pragma unroll
        for (int l = 0; l < 3; ++l) {
          int s4 = i*9 + j*3 + l;
          unsigned int kv = kvp[(i*25 + j*5 + l)*64];
          float kf = __uint_as_float(kv & 0xFFFF0000u);
          float vf = __uint_as_float(kv << 16);
          float pf = __builtin_amdgcn_exp2f(fmaf(q2, kf, -maxv));
          if (s4 & 1) { s1 += pf; o1 = fmaf(pf, vf, o1); }
          else        { s0 += pf; o0 = fmaf(pf, vf, o0); }
        }
    const float att = (o0 + o1) * __builtin_amdgcn_rcpf(s0 + s1);

    als[w*64 + c] = att;                  // wave-local broadcast buffer
    float g0 = GXb[p*64 + c] + bg_c, g1 = 0.f, g2 = 0.f, g3 = 0.f;
    #pragma unroll
    for (int j4 = 0; j4 < 16; ++j4) {
      const float4 a4 = *(const float4*)&als[w*64 + j4*4];  // same-addr broadcast
      g0 = fmaf(wg2reg[j4*4+0], a4.x, g0);
      g1 = fmaf(wg2reg[j4*4+1], a4.y, g1);
      g2 = fmaf(wg2reg[j4*4+2], a4.z, g2);
      g3 = fmaf(wg2reg[j4*4+3], a4.w, g3);
    }
    const float gl   = (g0 + g1) + (g2 + g3);
    const float gate = __builtin_amdgcn_rcpf(1.0f + __builtin_amdgcn_exp2f(-LOG2E * gl));
    const float xv   = XT[p*64 + c];
    const float fin  = fmaf(gate, att - xv, xv);
    QOT[p*64 + c] = fin;                  // coalesced full-line (N,C) store
    pacc += fin;
  }

  // pool reduce: 4 waves -> 64 lanes -> 64 device atomics
  als[t] = pacc;
  __syncthreads();
  if (t < 64) {
    float s = als[t] + als[64 + t] + als[128 + t] + als[192 + t];
    atomicAdd(&pool[b*64 + t], s);
  }
}

// ---------------------------------------------------------------------------
// Kernel 3: (N,C) -> (B,C,N) transpose through padded LDS (full-line reads
// AND writes). Block 0 additionally runs the GRU cell (pool is complete —
// stream-ordered after attn).
// ---------------------------------------------------------------------------
__global__ __launch_bounds__(256) void outpool_kernel(
    const float* __restrict__ OT, float* __restrict__ out,
    const float* __restrict__ pool, const float* __restrict__ prev,
    const float* __restrict__ W_ih, const float* __restrict__ W_hh,
    const float* __restrict__ b_ih, const float* __restrict__ b_hh,
    float* __restrict__ outmem)
{
  __shared__ __align__(16) float ls[64*65];
  __shared__ __align__(16) float mu[128];
  __shared__ float gi[384];
  __shared__ float gh[384];
  const int t  = threadIdx.x;
  const int bi = blockIdx.x;
  const int b  = bi / 216;
  const int n0 = (bi - b*216) * 64;
  #pragma unroll
  for (int i = 0; i < 16; ++i) {
    int u = i*256 + t;
    int pos = u >> 6, cc = u & 63;
    ls[cc*65 + pos] = OT[(size_t)(b*NPOS + n0 + pos)*64 + cc];  // coalesced read
  }
  if (bi == 0 && t < 128) mu[t] = pool[t] * (1.0f / (float)NPOS);
  __syncthreads();
  #pragma unroll
  for (int i = 0; i < 16; ++i) {
    int u = i*256 + t;
    int cc = u >> 6, j = u & 63;
    out[(size_t)(b*64 + cc)*NPOS + n0 + j] = ls[cc*65 + j];     // coalesced write
  }
  if (bi != 0) return;

  // ---- GRU cell (block 0 only) ----
  {
    int r = t; if (r < 384) {
      const int b2 = r / 192, j = r - b2*192;
      const float4* wi4 = (const float4*)(W_ih + (size_t)j*64);
      const float4* wh4 = (const float4*)(W_hh + (size_t)j*64);
      const float4* mu4 = (const float4*)(mu + b2*64);
      const float4* pv4 = (const float4*)(prev + b2*64);
      float sgi = b_ih[j], sgh = b_hh[j];
      #pragma unroll
      for (int k = 0; k < 16; ++k) {
        float4 wv = wi4[k], m4 = mu4[k];
        sgi = fmaf(wv.x, m4.x, sgi); sgi = fmaf(wv.y, m4.y, sgi);
        sgi = fmaf(wv.z, m4.z, sgi); sgi = fmaf(wv.w, m4.w, sgi);
        float4 hv = wh4[k], p4 = pv4[k];
        sgh = fmaf(hv.x, p4.x, sgh); sgh = fmaf(hv.y, p4.y, sgh);
        sgh = fmaf(hv.z, p4.z, sgh); sgh = fmaf(hv.w, p4.w, sgh);
      }
      gi[r] = sgi; gh[r] = sgh;
    }
    // threads 256..383 equivalent work: cover remaining rows with first 128
    if (t < 128) {
      const int r2 = 256 + t;
      const int b2 = r2 / 192, j = r2 - b2*192;
      const float4* wi4 = (const float4*)(W_ih + (size_t)j*64);
      const float4* wh4 = (const float4*)(W_hh + (size_t)j*64);
      const float4* mu4 = (const float4*)(mu + b2*64);
      const float4* pv4 = (const float4*)(prev + b2*64);
      float sgi = b_ih[j], sgh = b_hh[j];
      #pragma unroll
      for (int k = 0; k < 16; ++k) {
        float4 wv = wi4[k], m4 = mu4[k];
        sgi = fmaf(wv.x, m4.x, sgi); sgi = fmaf(wv.y, m4.y, sgi);
        sgi = fmaf(wv.z, m4.z, sgi); sgi = fmaf(wv.w, m4.w, sgi);
        float4 hv = wh4[k], p4 = pv4[k];
        sgh = fmaf(hv.x, p4.x, sgh); sgh = fmaf(hv.y, p4.y, sgh);
        sgh = fmaf(hv.z, p4.z, sgh); sgh = fmaf(hv.w, p4.w, sgh);
      }
      gi[r2] = sgi; gh[r2] = sgh;
    }
  }
  __syncthreads();
  if (t < 128) {
    const int b2 = t >> 6, cc = t & 63;
    float ir = gi[b2*192 + cc],       hr = gh[b2*192 + cc];
    float iz = gi[b2*192 + 64 + cc],  hz = gh[b2*192 + 64 + cc];
    float ii = gi[b2*192 + 128 + cc], hn = gh[b2*192 + 128 + cc];
    float rr = 1.0f / (1.0f + __builtin_amdgcn_exp2f(-LOG2E * (ir + hr)));
    float zz = 1.0f / (1.0f + __builtin_amdgcn_exp2f(-LOG2E * (iz + hz)));
    float ng = tanhf(ii + rr * hn);
    outmem[t] = (1.0f - zz) * ng + zz * prev[t];
  }
}

// ---------------------------------------------------------------------------
extern "C" void kernel_launch(void* const* d_in, const int* in_sizes, int n_in,
                              void* d_out, int out_size, void* d_ws, size_t ws_size,
                              hipStream_t stream) {
  const float* x    = (const float*)d_in[0];
  const float* prev = (const float*)d_in[1];
  const float* Wq   = (const float*)d_in[2];
  const float* bq   = (const float*)d_in[3];
  const float* Wk   = (const float*)d_in[4];
  const float* bk   = (const float*)d_in[5];
  const float* Wv   = (const float*)d_in[6];
  const float* bv   = (const float*)d_in[7];
  const float* memk = (const float*)d_in[8];
  const float* memv = (const float*)d_in[9];
  const float* Wg   = (const float*)d_in[10];
  const float* bg   = (const float*)d_in[11];
  const float* W_ih = (const float*)d_in[12];
  const float* W_hh = (const float*)d_in[13];
  const float* b_ih = (const float*)d_in[14];
  const float* b_hh = (const float*)d_in[15];

  float* out    = (float*)d_out;                 // (B,C,H,D,W)
  float* outmem = out + (size_t)BTCH*CDIM*NPOS;  // (B,C)

  const size_t SZ = (size_t)BTCH*NPOS*CDIM;      // 1769472
  float* wsf  = (float*)d_ws;
  float* Qb   = wsf;                             // also attn output (OT)
  float* Kb   = wsf + SZ;
  float* Vb   = wsf + 2*SZ;
  float* GXb  = wsf + 3*SZ;
  float* XT   = wsf + 4*SZ;
  float* pool = wsf + 5*SZ;                      // 128 floats

  qkvg_kernel<<<BTCH*216, 256, 0, stream>>>(x, Wq, bq, Wk, bk, Wv, bv, Wg,
                                            Qb, Kb, Vb, GXb, XT, pool);
  attn_kernel<<<BTCH*512, 256, 0, stream>>>(Qb, Kb, Vb, GXb, XT,
                                            bk, bv, memk, memv, Wg, bg, pool);
  outpool_kernel<<<BTCH*216, 256, 0, stream>>>(Qb, out, pool, prev,
                                               W_ih, W_hh, b_ih, b_hh, outmem);
}

// Round 6
// 169.421 us; speedup vs baseline: 1.2733x; 1.0278x over previous
//
#include <hip/hip_runtime.h>
#include <math.h>

#define NPOS 13824   // 24*24*24
#define CDIM 64
#define BTCH 2
#define LOG2E 1.4426950408889634f
#define QSCALE (0.125f * LOG2E)

__device__ __forceinline__ unsigned int f2bf1(float f) {   // RNE float->bf16
  unsigned int u = __float_as_uint(f);
  return (u + 0x7FFFu + ((u >> 16) & 1u)) >> 16;
}

// ---------------------------------------------------------------------------
// Kernel 1: Q/K/V projections + packed (gateX, x) buffer GXT, all in (B,N,C)
// layout. Q pre-scaled by 0.125*log2(e). Zeroes pool.
// ---------------------------------------------------------------------------
__global__ __launch_bounds__(256) void qkvg_kernel(
    const float* __restrict__ x,
    const float* __restrict__ Wq, const float* __restrict__ bq,
    const float* __restrict__ Wk, const float* __restrict__ bk,
    const float* __restrict__ Wv, const float* __restrict__ bv,
    const float* __restrict__ Wg,
    float* __restrict__ Qb, float* __restrict__ Kb, float* __restrict__ Vb,
    float* __restrict__ GXT, float* __restrict__ pool)
{
  __shared__ __align__(16) float wqt[64*68];
  __shared__ __align__(16) float wkt[64*68];
  __shared__ __align__(16) float wvt[64*68];
  __shared__ __align__(16) float wgt[64*68];
  const int t  = threadIdx.x;
  const int bi = blockIdx.x;
  const int b  = bi / 216;
  const int n0 = (bi - b*216) * 64;
  if (bi == 0 && t < 128) pool[t] = 0.0f;

  #pragma unroll
  for (int k = 0; k < 16; ++k) {
    int idx = t + k*256;                 // 0..4095
    int lo = idx & 63, hi = idx >> 6;
    wqt[lo*68 + hi] = Wq[idx] * QSCALE;  // [c_in][c_out], Q pre-scaled
    wkt[lo*68 + hi] = Wk[idx];
    wvt[lo*68 + hi] = Wv[idx];
    wgt[lo*68 + hi] = Wg[hi*128 + lo];   // first 64 columns of Wg
  }
  __syncthreads();

  const int c0  = (t & 15) * 4;          // 4 output channels
  const int nn0 = (t >> 4) * 4;          // 4 positions
  const float* xbase = x + (size_t)(b*64)*NPOS + n0 + nn0;
  float aq[4][4] = {}; float ak[4][4] = {}; float av[4][4] = {}; float ag[4][4] = {};
  #pragma unroll 4
  for (int cp = 0; cp < 64; ++cp) {
    const float4 xv4 = *(const float4*)(xbase + (size_t)cp*NPOS);
    const float4 q4  = *(const float4*)&wqt[cp*68 + c0];
    const float4 k4  = *(const float4*)&wkt[cp*68 + c0];
    const float4 v4  = *(const float4*)&wvt[cp*68 + c0];
    const float4 g4  = *(const float4*)&wgt[cp*68 + c0];
    const float xa[4] = {xv4.x, xv4.y, xv4.z, xv4.w};
    const float qa[4] = {q4.x, q4.y, q4.z, q4.w};
    const float ka[4] = {k4.x, k4.y, k4.z, k4.w};
    const float va[4] = {v4.x, v4.y, v4.z, v4.w};
    const float ga[4] = {g4.x, g4.y, g4.z, g4.w};
    #pragma unroll
    for (int ci = 0; ci < 4; ++ci)
      #pragma unroll
      for (int ni = 0; ni < 4; ++ni) {
        aq[ci][ni] = fmaf(qa[ci], xa[ni], aq[ci][ni]);
        ak[ci][ni] = fmaf(ka[ci], xa[ni], ak[ci][ni]);
        av[ci][ni] = fmaf(va[ci], xa[ni], av[ci][ni]);
        ag[ci][ni] = fmaf(ga[ci], xa[ni], ag[ci][ni]);
      }
  }
  // re-read x tile rows c0..c0+3 (L1-hot) for the packed x half of GXT
  float4 xr[4];
  #pragma unroll
  for (int e = 0; e < 4; ++e)
    xr[e] = *(const float4*)(x + (size_t)(b*64 + c0 + e)*NPOS + n0 + nn0);
  const float xre[4][4] = {{xr[0].x,xr[0].y,xr[0].z,xr[0].w},
                           {xr[1].x,xr[1].y,xr[1].z,xr[1].w},
                           {xr[2].x,xr[2].y,xr[2].z,xr[2].w},
                           {xr[3].x,xr[3].y,xr[3].z,xr[3].w}};
  const float4 bq4 = *(const float4*)&bq[c0];
  const float4 bk4 = *(const float4*)&bk[c0];
  const float4 bv4 = *(const float4*)&bv[c0];
  #pragma unroll
  for (int ni = 0; ni < 4; ++ni) {
    const int p = b*NPOS + n0 + nn0 + ni;   // (N,C) layout: [p*64 + c]
    float4 o;
    o = make_float4(fmaf(bq4.x,QSCALE,aq[0][ni]), fmaf(bq4.y,QSCALE,aq[1][ni]),
                    fmaf(bq4.z,QSCALE,aq[2][ni]), fmaf(bq4.w,QSCALE,aq[3][ni]));
    *(float4*)&Qb[p*64 + c0] = o;
    o = make_float4(ak[0][ni]+bk4.x, ak[1][ni]+bk4.y, ak[2][ni]+bk4.z, ak[3][ni]+bk4.w);
    *(float4*)&Kb[p*64 + c0] = o;
    o = make_float4(av[0][ni]+bv4.x, av[1][ni]+bv4.y, av[2][ni]+bv4.z, av[3][ni]+bv4.w);
    *(float4*)&Vb[p*64 + c0] = o;
    // GXT: interleaved {gateX, x} per (p,c); bg added in attn
    o = make_float4(ag[0][ni], xre[0][ni], ag[1][ni], xre[1][ni]);
    *(float4*)&GXT[(size_t)(p*64 + c0)*2]     = o;
    o = make_float4(ag[2][ni], xre[2][ni], ag[3][ni], xre[3][ni]);
    *(float4*)&GXT[(size_t)(p*64 + c0)*2 + 4] = o;
  }
}

// ---------------------------------------------------------------------------
// Kernel 2: tiled attention. XCD-swizzled 3x3x3 tiles; 5x5x5 bf16-packed K|V
// halo in LDS (31.25 KB, 4 blocks/CU). Gate weights bf16-packed in 32 VGPRs.
// Software-pipelined per-position loop; pass 2 runs from a 27-dword register
// stash. Coalesced (N,C) result into QOT (aliases Qb).
// ---------------------------------------------------------------------------
__global__ __launch_bounds__(256, 4) void attn_kernel(
    float* __restrict__ QOT,             // in: Q (N,C, pre-scaled); out: fin
    const float* __restrict__ Kb, const float* __restrict__ Vb,
    const float* __restrict__ GXT,
    const float* __restrict__ bk, const float* __restrict__ bv,
    const float* __restrict__ memk, const float* __restrict__ memv,
    const float* __restrict__ Wg, const float* __restrict__ bg,
    float* __restrict__ pool)
{
  __shared__ __align__(16) unsigned int kvbuf[8000]; // 125 slots x 64 ch, bf16 K|V
  __shared__ __align__(16) float als[256];
  const int t = threadIdx.x;
  const int c = t & 63;
  const int w = t >> 6;

  // stage Wg[:,64:] via padded-65 LDS transpose (overlay kvbuf), pack to bf16
  {
    float* wgt2 = (float*)kvbuf;
    #pragma unroll
    for (int k = 0; k < 16; ++k) {
      int u = t + k*256;
      int cp = u >> 6, j = u & 63;
      wgt2[j*65 + cp] = Wg[cp*128 + 64 + j];
    }
  }
  __syncthreads();
  unsigned int wg2p[32];                 // bf16 pair: lo=even j, hi=odd j
  {
    const float* wgt2 = (const float*)kvbuf;
    #pragma unroll
    for (int j2 = 0; j2 < 32; ++j2) {
      unsigned lo = f2bf1(wgt2[(2*j2)*65 + c]);
      unsigned hi = f2bf1(wgt2[(2*j2+1)*65 + c]);
      wg2p[j2] = lo | (hi << 16);
    }
  }
  float mk[5], mv[5];
  #pragma unroll
  for (int m = 0; m < 5; ++m) { mk[m] = memk[c*5 + m]; mv[m] = memv[c*5 + m]; }
  const float bg_c = bg[c];
  __syncthreads();

  // XCD-aware swizzle: round-robin dispatch -> bi&7 = XCD; give each XCD a
  // contiguous slab of 128 tiles so the K/V halo stays in its 4 MB L2.
  const int bi = (int)(blockIdx.x & 7) * 128 + (int)(blockIdx.x >> 3);
  const int b  = bi >> 9;                 // 512 tiles (8x8x8) per batch
  const int tb = bi & 511;
  const int h0 = (tb >> 6) * 3;
  const int d0 = ((tb >> 3) & 7) * 3;
  const int w0 = (tb & 7) * 3;
  const int bN = b * NPOS;

  // stage 5x5x5 packed K/V halo (OOB -> bias)
  for (int u = t; u < 125*16; u += 256) {
    int pos = u >> 4, q4 = u & 15;
    int ph = pos / 25, pr = pos - ph*25;
    int pd = pr / 5,  pw = pr - pd*5;
    int hh = h0 - 1 + ph, dd = d0 - 1 + pd, ww = w0 - 1 + pw;
    bool inb = ((unsigned)hh < 24u) && ((unsigned)dd < 24u) && ((unsigned)ww < 24u);
    float4 kf, vf;
    if (inb) {
      const size_t off = ((size_t)(bN + hh*576 + dd*24 + ww))*64 + q4*4;
      kf = *(const float4*)(Kb + off);
      vf = *(const float4*)(Vb + off);
    } else {
      kf = ((const float4*)bk)[q4];
      vf = ((const float4*)bv)[q4];
    }
    uint4 pk;
    pk.x = (f2bf1(kf.x) << 16) | f2bf1(vf.x);
    pk.y = (f2bf1(kf.y) << 16) | f2bf1(vf.y);
    pk.z = (f2bf1(kf.z) << 16) | f2bf1(vf.z);
    pk.w = (f2bf1(kf.w) << 16) | f2bf1(vf.w);
    *(uint4*)&kvbuf[pos*64 + q4*4] = pk;
  }
  __syncthreads();

  float pacc = 0.0f;
  // software-pipelined position loop: li = w, w+4, ..., <27
  int li = w;
  int lh = li / 9, lr = li - lh*9, ld = lr / 3, lw = lr - ld*3;
  int p  = bN + (h0+lh)*576 + (d0+ld)*24 + (w0+lw);
  int hb = (lh*25 + ld*5 + lw)*64 + c;
  float q2 = QOT[p*64 + c];
  for (; li < 27; li += 4) {
    // prefetch next position's Q
    const int li_n = li + 4;
    int p_n = p, hb_n = hb;
    if (li_n < 27) {
      const int lh2 = li_n / 9, lr2 = li_n - lh2*9;
      const int ld2 = lr2 / 3,  lw2 = lr2 - ld2*3;
      p_n  = bN + (h0+lh2)*576 + (d0+ld2)*24 + (w0+lw2);
      hb_n = (lh2*25 + ld2*5 + lw2)*64 + c;
    }
    const float q_n = QOT[p_n*64 + c];
    // issue gate/x load now; consumed ~700 cycles later
    const float2 gx = *(const float2*)&GXT[(size_t)(p*64 + c)*2];

    // pass 1: stash 27 packed K|V dwords, running max over 32 logits
    const unsigned int* kvp = &kvbuf[hb];
    unsigned int kvreg[27];
    #pragma unroll
    for (int i = 0; i < 3; ++i)
      #pragma unroll
      for (int j = 0; j < 3; ++j)
        #pragma unroll
        for (int l = 0; l < 3; ++l)
          kvreg[i*9 + j*3 + l] = kvp[(i*25 + j*5 + l)*64];
    float mx0 = q2*mk[0], mx1 = q2*mk[1], mx2 = q2*mk[2], mx3 = q2*mk[3];
    mx0 = fmaxf(mx0, q2*mk[4]);
    #pragma unroll
    for (int s = 0; s < 27; ++s) {
      float kf = __uint_as_float(kvreg[s] & 0xFFFF0000u);
      float lv = q2 * kf;
      if ((s & 3) == 0) mx0 = fmaxf(mx0, lv);
      else if ((s & 3) == 1) mx1 = fmaxf(mx1, lv);
      else if ((s & 3) == 2) mx2 = fmaxf(mx2, lv);
      else mx3 = fmaxf(mx3, lv);
    }
    const float maxv = fmaxf(fmaxf(mx0, mx1), fmaxf(mx2, mx3));

    // pass 2: exp-sum + weighted values, all from registers
    float s0 = 0.f, s1 = 0.f, o0 = 0.f, o1 = 0.f;
    #pragma unroll
    for (int m = 0; m < 5; ++m) {
      float pf = __builtin_amdgcn_exp2f(fmaf(q2, mk[m], -maxv));
      if (m & 1) { s1 += pf; o1 = fmaf(pf, mv[m], o1); }
      else       { s0 += pf; o0 = fmaf(pf, mv[m], o0); }
    }
    #pragma unroll
    for (int s = 0; s < 27; ++s) {
      unsigned int kv = kvreg[s];
      float kf = __uint_as_float(kv & 0xFFFF0000u);
      float vf = __uint_as_float(kv << 16);
      float pf = __builtin_amdgcn_exp2f(fmaf(q2, kf, -maxv));
      if (s & 1) { s1 += pf; o1 = fmaf(pf, vf, o1); }
      else       { s0 += pf; o0 = fmaf(pf, vf, o0); }
    }
    const float att = (o0 + o1) * __builtin_amdgcn_rcpf(s0 + s1);

    als[w*64 + c] = att;                  // wave-local broadcast buffer
    float g0 = gx.x + bg_c, g1 = 0.f, g2 = 0.f, g3 = 0.f;
    #pragma unroll
    for (int j4 = 0; j4 < 16; ++j4) {
      const float4 a4 = *(const float4*)&als[w*64 + j4*4];  // same-addr broadcast
      const unsigned pk0 = wg2p[2*j4], pk1 = wg2p[2*j4+1];
      g0 = fmaf(__uint_as_float(pk0 << 16),         a4.x, g0);
      g1 = fmaf(__uint_as_float(pk0 & 0xFFFF0000u), a4.y, g1);
      g2 = fmaf(__uint_as_float(pk1 << 16),         a4.z, g2);
      g3 = fmaf(__uint_as_float(pk1 & 0xFFFF0000u), a4.w, g3);
    }
    const float gl   = (g0 + g1) + (g2 + g3);
    const float gate = __builtin_amdgcn_rcpf(1.0f + __builtin_amdgcn_exp2f(-LOG2E * gl));
    const float fin  = fmaf(gate, att - gx.y, gx.y);
    QOT[p*64 + c] = fin;                  // coalesced full-line (N,C) store
    pacc += fin;

    p = p_n; hb = hb_n; q2 = q_n;
  }

  // pool reduce: 4 waves -> 64 lanes -> 64 device atomics
  als[t] = pacc;
  __syncthreads();
  if (t < 64) {
    float s = als[t] + als[64 + t] + als[128 + t] + als[192 + t];
    atomicAdd(&pool[b*64 + t], s);
  }
}

// ---------------------------------------------------------------------------
// Kernel 3: (N,C) -> (B,C,N) transpose through padded LDS (full-line reads
// AND writes). Block 0 additionally runs the GRU cell.
// ---------------------------------------------------------------------------
__global__ __launch_bounds__(256) void outpool_kernel(
    const float* __restrict__ OT, float* __restrict__ out,
    const float* __restrict__ pool, const float* __restrict__ prev,
    const float* __restrict__ W_ih, const float* __restrict__ W_hh,
    const float* __restrict__ b_ih, const float* __restrict__ b_hh,
    float* __restrict__ outmem)
{
  __shared__ __align__(16) float ls[64*65];
  __shared__ __align__(16) float mu[128];
  __shared__ float gi[384];
  __shared__ float gh[384];
  const int t  = threadIdx.x;
  const int bi = blockIdx.x;
  const int b  = bi / 216;
  const int n0 = (bi - b*216) * 64;
  #pragma unroll
  for (int i = 0; i < 16; ++i) {
    int u = i*256 + t;
    int pos = u >> 6, cc = u & 63;
    ls[cc*65 + pos] = OT[(size_t)(b*NPOS + n0 + pos)*64 + cc];  // coalesced read
  }
  if (bi == 0 && t < 128) mu[t] = pool[t] * (1.0f / (float)NPOS);
  __syncthreads();
  #pragma unroll
  for (int i = 0; i < 16; ++i) {
    int u = i*256 + t;
    int cc = u >> 6, j = u & 63;
    out[(size_t)(b*64 + cc)*NPOS + n0 + j] = ls[cc*65 + j];     // coalesced write
  }
  if (bi != 0) return;

  // ---- GRU cell (block 0 only) ----
  for (int r = t; r < 384; r += 256) {
    const int b2 = r / 192, j = r - b2*192;
    const float4* wi4 = (const float4*)(W_ih + (size_t)j*64);
    const float4* wh4 = (const float4*)(W_hh + (size_t)j*64);
    const float4* mu4 = (const float4*)(mu + b2*64);
    const float4* pv4 = (const float4*)(prev + b2*64);
    float sgi = b_ih[j], sgh = b_hh[j];
    #pragma unroll
    for (int k = 0; k < 16; ++k) {
      float4 wv = wi4[k], m4 = mu4[k];
      sgi = fmaf(wv.x, m4.x, sgi); sgi = fmaf(wv.y, m4.y, sgi);
      sgi = fmaf(wv.z, m4.z, sgi); sgi = fmaf(wv.w, m4.w, sgi);
      float4 hv = wh4[k], p4 = pv4[k];
      sgh = fmaf(hv.x, p4.x, sgh); sgh = fmaf(hv.y, p4.y, sgh);
      sgh = fmaf(hv.z, p4.z, sgh); sgh = fmaf(hv.w, p4.w, sgh);
    }
    gi[r] = sgi; gh[r] = sgh;
  }
  __syncthreads();
  if (t < 128) {
    const int b2 = t >> 6, cc = t & 63;
    float ir = gi[b2*192 + cc],       hr = gh[b2*192 + cc];
    float iz = gi[b2*192 + 64 + cc],  hz = gh[b2*192 + 64 + cc];
    float ii = gi[b2*192 + 128 + cc], hn = gh[b2*192 + 128 + cc];
    float rr = 1.0f / (1.0f + __builtin_amdgcn_exp2f(-LOG2E * (ir + hr)));
    float zz = 1.0f / (1.0f + __builtin_amdgcn_exp2f(-LOG2E * (iz + hz)));
    float ng = tanhf(ii + rr * hn);
    outmem[t] = (1.0f - zz) * ng + zz * prev[t];
  }
}

// ---------------------------------------------------------------------------
extern "C" void kernel_launch(void* const* d_in, const int* in_sizes, int n_in,
                              void* d_out, int out_size, void* d_ws, size_t ws_size,
                              hipStream_t stream) {
  const float* x    = (const float*)d_in[0];
  const float* prev = (const float*)d_in[1];
  const float* Wq   = (const float*)d_in[2];
  const float* bq   = (const float*)d_in[3];
  const float* Wk   = (const float*)d_in[4];
  const float* bk   = (const float*)d_in[5];
  const float* Wv   = (const float*)d_in[6];
  const float* bv   = (const float*)d_in[7];
  const float* memk = (const float*)d_in[8];
  const float* memv = (const float*)d_in[9];
  const float* Wg   = (const float*)d_in[10];
  const float* bg   = (const float*)d_in[11];
  const float* W_ih = (const float*)d_in[12];
  const float* W_hh = (const float*)d_in[13];
  const float* b_ih = (const float*)d_in[14];
  const float* b_hh = (const float*)d_in[15];

  float* out    = (float*)d_out;                 // (B,C,H,D,W)
  float* outmem = out + (size_t)BTCH*CDIM*NPOS;  // (B,C)

  const size_t SZ = (size_t)BTCH*NPOS*CDIM;      // 1769472
  float* wsf  = (float*)d_ws;
  float* Qb   = wsf;                             // also attn output (OT)
  float* Kb   = wsf + SZ;
  float* Vb   = wsf + 2*SZ;
  float* GXT  = wsf + 3*SZ;                      // float2 per element: 2*SZ
  float* pool = wsf + 5*SZ;                      // 128 floats

  qkvg_kernel<<<BTCH*216, 256, 0, stream>>>(x, Wq, bq, Wk, bk, Wv, bv, Wg,
                                            Qb, Kb, Vb, GXT, pool);
  attn_kernel<<<BTCH*512, 256, 0, stream>>>(Qb, Kb, Vb, GXT,
                                            bk, bv, memk, memv, Wg, bg, pool);
  outpool_kernel<<<BTCH*216, 256, 0, stream>>>(Qb, out, pool, prev,
                                               W_ih, W_hh, b_ih, b_hh, outmem);
}

// Round 7
// 150.190 us; speedup vs baseline: 1.4363x; 1.1280x over previous
//
#include <hip/hip_runtime.h>
#include <math.h>

#define NPOS 13824   // 24*24*24
#define CDIM 64
#define BTCH 2
#define LOG2E 1.4426950408889634f
#define QSCALE (0.125f * LOG2E)

__device__ __forceinline__ unsigned int f2bf1(float f) {   // RNE float->bf16
  unsigned int u = __float_as_uint(f);
  return (u + 0x7FFFu + ((u >> 16) & 1u)) >> 16;
}

// ---------------------------------------------------------------------------
// Kernel 1: Q projection (pre-scaled by 0.125*log2e), bf16-packed K|V
// (bias included), and packed (gateX, x) float2 buffer GXT — all (B,N,C).
// Zeroes pool.
// ---------------------------------------------------------------------------
__global__ __launch_bounds__(256) void qkvg_kernel(
    const float* __restrict__ x,
    const float* __restrict__ Wq, const float* __restrict__ bq,
    const float* __restrict__ Wk, const float* __restrict__ bk,
    const float* __restrict__ Wv, const float* __restrict__ bv,
    const float* __restrict__ Wg,
    float* __restrict__ Qb, unsigned int* __restrict__ KVp,
    float* __restrict__ GXT, float* __restrict__ pool)
{
  __shared__ __align__(16) float wqt[64*68];
  __shared__ __align__(16) float wkt[64*68];
  __shared__ __align__(16) float wvt[64*68];
  __shared__ __align__(16) float wgt[64*68];
  const int t  = threadIdx.x;
  const int bi = blockIdx.x;
  const int b  = bi / 216;
  const int n0 = (bi - b*216) * 64;
  if (bi == 0 && t < 128) pool[t] = 0.0f;

  #pragma unroll
  for (int k = 0; k < 16; ++k) {
    int idx = t + k*256;                 // 0..4095
    int lo = idx & 63, hi = idx >> 6;
    wqt[lo*68 + hi] = Wq[idx] * QSCALE;  // [c_in][c_out], Q pre-scaled
    wkt[lo*68 + hi] = Wk[idx];
    wvt[lo*68 + hi] = Wv[idx];
    wgt[lo*68 + hi] = Wg[hi*128 + lo];   // first 64 columns of Wg
  }
  __syncthreads();

  const int c0  = (t & 15) * 4;          // 4 output channels
  const int nn0 = (t >> 4) * 4;          // 4 positions
  const float* xbase = x + (size_t)(b*64)*NPOS + n0 + nn0;
  float aq[4][4] = {}; float ak[4][4] = {}; float av[4][4] = {}; float ag[4][4] = {};
  #pragma unroll 4
  for (int cp = 0; cp < 64; ++cp) {
    const float4 xv4 = *(const float4*)(xbase + (size_t)cp*NPOS);
    const float4 q4  = *(const float4*)&wqt[cp*68 + c0];
    const float4 k4  = *(const float4*)&wkt[cp*68 + c0];
    const float4 v4  = *(const float4*)&wvt[cp*68 + c0];
    const float4 g4  = *(const float4*)&wgt[cp*68 + c0];
    const float xa[4] = {xv4.x, xv4.y, xv4.z, xv4.w};
    const float qa[4] = {q4.x, q4.y, q4.z, q4.w};
    const float ka[4] = {k4.x, k4.y, k4.z, k4.w};
    const float va[4] = {v4.x, v4.y, v4.z, v4.w};
    const float ga[4] = {g4.x, g4.y, g4.z, g4.w};
    #pragma unroll
    for (int ci = 0; ci < 4; ++ci)
      #pragma unroll
      for (int ni = 0; ni < 4; ++ni) {
        aq[ci][ni] = fmaf(qa[ci], xa[ni], aq[ci][ni]);
        ak[ci][ni] = fmaf(ka[ci], xa[ni], ak[ci][ni]);
        av[ci][ni] = fmaf(va[ci], xa[ni], av[ci][ni]);
        ag[ci][ni] = fmaf(ga[ci], xa[ni], ag[ci][ni]);
      }
  }
  // re-read x tile rows c0..c0+3 (L1-hot) for the x half of GXT
  float4 xr[4];
  #pragma unroll
  for (int e = 0; e < 4; ++e)
    xr[e] = *(const float4*)(x + (size_t)(b*64 + c0 + e)*NPOS + n0 + nn0);
  const float xre[4][4] = {{xr[0].x,xr[0].y,xr[0].z,xr[0].w},
                           {xr[1].x,xr[1].y,xr[1].z,xr[1].w},
                           {xr[2].x,xr[2].y,xr[2].z,xr[2].w},
                           {xr[3].x,xr[3].y,xr[3].z,xr[3].w}};
  const float4 bq4 = *(const float4*)&bq[c0];
  const float4 bk4 = *(const float4*)&bk[c0];
  const float4 bv4 = *(const float4*)&bv[c0];
  #pragma unroll
  for (int ni = 0; ni < 4; ++ni) {
    const int p = b*NPOS + n0 + nn0 + ni;   // (N,C) layout: [p*64 + c]
    float4 o;
    o = make_float4(fmaf(bq4.x,QSCALE,aq[0][ni]), fmaf(bq4.y,QSCALE,aq[1][ni]),
                    fmaf(bq4.z,QSCALE,aq[2][ni]), fmaf(bq4.w,QSCALE,aq[3][ni]));
    *(float4*)&Qb[p*64 + c0] = o;
    // packed bf16 K (hi) | V (lo), bias included
    uint4 kv;
    kv.x = (f2bf1(ak[0][ni]+bk4.x) << 16) | f2bf1(av[0][ni]+bv4.x);
    kv.y = (f2bf1(ak[1][ni]+bk4.y) << 16) | f2bf1(av[1][ni]+bv4.y);
    kv.z = (f2bf1(ak[2][ni]+bk4.z) << 16) | f2bf1(av[2][ni]+bv4.z);
    kv.w = (f2bf1(ak[3][ni]+bk4.w) << 16) | f2bf1(av[3][ni]+bv4.w);
    *(uint4*)&KVp[p*64 + c0] = kv;
    // GXT: interleaved {gateX, x} per (p,c); bg added in attn
    o = make_float4(ag[0][ni], xre[0][ni], ag[1][ni], xre[1][ni]);
    *(float4*)&GXT[(size_t)(p*64 + c0)*2]     = o;
    o = make_float4(ag[2][ni], xre[2][ni], ag[3][ni], xre[3][ni]);
    *(float4*)&GXT[(size_t)(p*64 + c0)*2 + 4] = o;
  }
}

// ---------------------------------------------------------------------------
// Kernel 2: tiled attention. XCD-swizzled 3x3x3 tiles; 5x5x5 bf16-packed K|V
// halo in LDS (31.25 KB, 4 blocks/CU). NO max pass (|logit| <= ~2, exp2 is
// safe; softmax is shift-invariant). Single streaming softmax pass, TWO
// positions per wave iteration for ILP. Gate weights bf16-packed in VGPRs.
// Coalesced (N,C) result into QOT (aliases Qb).
// ---------------------------------------------------------------------------
__global__ __launch_bounds__(256, 4) void attn_kernel(
    float* __restrict__ QOT,             // in: Q (N,C, pre-scaled); out: fin
    const unsigned int* __restrict__ KVp,
    const float* __restrict__ GXT,
    const float* __restrict__ bk, const float* __restrict__ bv,
    const float* __restrict__ memk, const float* __restrict__ memv,
    const float* __restrict__ Wg, const float* __restrict__ bg,
    float* __restrict__ pool)
{
  __shared__ __align__(16) unsigned int kvbuf[8000]; // 125 slots x 64 ch, bf16 K|V
  __shared__ __align__(16) float alsA[256];
  __shared__ __align__(16) float alsB[256];
  const int t = threadIdx.x;
  const int c = t & 63;
  const int w = t >> 6;

  // stage Wg[:,64:] via padded-65 LDS transpose (overlay kvbuf), pack to bf16
  {
    float* wgt2 = (float*)kvbuf;
    #pragma unroll
    for (int k = 0; k < 16; ++k) {
      int u = t + k*256;
      int cp = u >> 6, j = u & 63;
      wgt2[j*65 + cp] = Wg[cp*128 + 64 + j];
    }
  }
  __syncthreads();
  unsigned int wg2p[32];                 // bf16 pair: lo=even j, hi=odd j
  {
    const float* wgt2 = (const float*)kvbuf;
    #pragma unroll
    for (int j2 = 0; j2 < 32; ++j2) {
      unsigned lo = f2bf1(wgt2[(2*j2)*65 + c]);
      unsigned hi = f2bf1(wgt2[(2*j2+1)*65 + c]);
      wg2p[j2] = lo | (hi << 16);
    }
  }
  float mk[5], mv[5];
  #pragma unroll
  for (int m = 0; m < 5; ++m) { mk[m] = memk[c*5 + m]; mv[m] = memv[c*5 + m]; }
  const float bg_c = bg[c];
  __syncthreads();

  // XCD-aware swizzle: bi&7 = XCD; contiguous 128-tile slab per XCD for L2 reuse
  const int bi = (int)(blockIdx.x & 7) * 128 + (int)(blockIdx.x >> 3);
  const int b  = bi >> 9;                 // 512 tiles (8x8x8) per batch
  const int tb = bi & 511;
  const int h0 = (tb >> 6) * 3;
  const int d0 = ((tb >> 3) & 7) * 3;
  const int w0 = (tb & 7) * 3;
  const int bN = b * NPOS;

  // stage 5x5x5 packed K/V halo (already bf16-packed in global; OOB -> bias)
  for (int u = t; u < 125*16; u += 256) {
    int pos = u >> 4, q4 = u & 15;
    int ph = pos / 25, pr = pos - ph*25;
    int pd = pr / 5,  pw = pr - pd*5;
    int hh = h0 - 1 + ph, dd = d0 - 1 + pd, ww = w0 - 1 + pw;
    bool inb = ((unsigned)hh < 24u) && ((unsigned)dd < 24u) && ((unsigned)ww < 24u);
    uint4 kv;
    if (inb) {
      kv = *(const uint4*)(KVp + ((size_t)(bN + hh*576 + dd*24 + ww))*64 + q4*4);
    } else {
      const float4 kf = ((const float4*)bk)[q4];
      const float4 vf = ((const float4*)bv)[q4];
      kv.x = (f2bf1(kf.x) << 16) | f2bf1(vf.x);
      kv.y = (f2bf1(kf.y) << 16) | f2bf1(vf.y);
      kv.z = (f2bf1(kf.z) << 16) | f2bf1(vf.z);
      kv.w = (f2bf1(kf.w) << 16) | f2bf1(vf.w);
    }
    *(uint4*)&kvbuf[pos*64 + q4*4] = kv;
  }
  __syncthreads();

  float pacc = 0.0f;
  // two positions (li, li+4) per iteration; independent chains for ILP
  for (int li = w; li < 27; li += 8) {
    const int liB0 = li + 4;
    const bool hasB = liB0 < 27;          // wave-uniform
    const int liB = hasB ? liB0 : li;

    const int lhA = li / 9,  lrA = li - lhA*9;
    const int ldA = lrA / 3, lwA = lrA - ldA*3;
    const int pA  = bN + (h0+lhA)*576 + (d0+ldA)*24 + (w0+lwA);
    const int hbA = (lhA*25 + ldA*5 + lwA)*64 + c;
    const int lhB = liB / 9,  lrB = liB - lhB*9;
    const int ldB = lrB / 3,  lwB = lrB - ldB*3;
    const int pB  = bN + (h0+lhB)*576 + (d0+ldB)*24 + (w0+lwB);
    const int hbB = (lhB*25 + ldB*5 + lwB)*64 + c;

    const float qA = QOT[pA*64 + c];      // pre-scaled by 0.125*log2e
    const float qB = QOT[pB*64 + c];
    const float2 gxA = *(const float2*)&GXT[(size_t)(pA*64 + c)*2];
    const float2 gxB = *(const float2*)&GXT[(size_t)(pB*64 + c)*2];

    // single-pass softmax (no max subtraction), both positions interleaved
    float sA0 = 0.f, sA1 = 0.f, oA0 = 0.f, oA1 = 0.f;
    float sB0 = 0.f, sB1 = 0.f, oB0 = 0.f, oB1 = 0.f;
    #pragma unroll
    for (int m = 0; m < 5; ++m) {
      const float pfA = __builtin_amdgcn_exp2f(qA * mk[m]);
      const float pfB = __builtin_amdgcn_exp2f(qB * mk[m]);
      if (m & 1) { sA1 += pfA; oA1 = fmaf(pfA, mv[m], oA1);
                   sB1 += pfB; oB1 = fmaf(pfB, mv[m], oB1); }
      else       { sA0 += pfA; oA0 = fmaf(pfA, mv[m], oA0);
                   sB0 += pfB; oB0 = fmaf(pfB, mv[m], oB0); }
    }
    const unsigned int* kvA = &kvbuf[hbA];
    const unsigned int* kvB = &kvbuf[hbB];
    #pragma unroll
    for (int i = 0; i < 3; ++i)
      #pragma unroll
      for (int j = 0; j < 3; ++j)
        #pragma unroll
        for (int l = 0; l < 3; ++l) {
          const int s4  = i*9 + j*3 + l;
          const int off = (i*25 + j*5 + l)*64;
          const unsigned a = kvA[off], bb2 = kvB[off];
          const float kA = __uint_as_float(a & 0xFFFF0000u);
          const float vA = __uint_as_float(a << 16);
          const float kB = __uint_as_float(bb2 & 0xFFFF0000u);
          const float vB = __uint_as_float(bb2 << 16);
          const float pfA = __builtin_amdgcn_exp2f(qA * kA);
          const float pfB = __builtin_amdgcn_exp2f(qB * kB);
          if (s4 & 1) { sA1 += pfA; oA1 = fmaf(pfA, vA, oA1);
                        sB1 += pfB; oB1 = fmaf(pfB, vB, oB1); }
          else        { sA0 += pfA; oA0 = fmaf(pfA, vA, oA0);
                        sB0 += pfB; oB0 = fmaf(pfB, vB, oB0); }
        }
    const float attA = (oA0 + oA1) * __builtin_amdgcn_rcpf(sA0 + sA1);
    const float attB = (oB0 + oB1) * __builtin_amdgcn_rcpf(sB0 + sB1);

    alsA[w*64 + c] = attA;                // wave-local broadcast buffers
    alsB[w*64 + c] = attB;
    float gA0 = gxA.x + bg_c, gA1 = 0.f, gA2 = 0.f, gA3 = 0.f;
    float gB0 = gxB.x + bg_c, gB1 = 0.f, gB2 = 0.f, gB3 = 0.f;
    #pragma unroll
    for (int j4 = 0; j4 < 16; ++j4) {
      const float4 a4 = *(const float4*)&alsA[w*64 + j4*4];
      const float4 b4 = *(const float4*)&alsB[w*64 + j4*4];
      const unsigned pk0 = wg2p[2*j4], pk1 = wg2p[2*j4+1];
      const float w0f = __uint_as_float(pk0 << 16);
      const float w1f = __uint_as_float(pk0 & 0xFFFF0000u);
      const float w2f = __uint_as_float(pk1 << 16);
      const float w3f = __uint_as_float(pk1 & 0xFFFF0000u);
      gA0 = fmaf(w0f, a4.x, gA0); gB0 = fmaf(w0f, b4.x, gB0);
      gA1 = fmaf(w1f, a4.y, gA1); gB1 = fmaf(w1f, b4.y, gB1);
      gA2 = fmaf(w2f, a4.z, gA2); gB2 = fmaf(w2f, b4.z, gB2);
      gA3 = fmaf(w3f, a4.w, gA3); gB3 = fmaf(w3f, b4.w, gB3);
    }
    const float glA   = (gA0 + gA1) + (gA2 + gA3);
    const float glB   = (gB0 + gB1) + (gB2 + gB3);
    const float gateA = __builtin_amdgcn_rcpf(1.0f + __builtin_amdgcn_exp2f(-LOG2E * glA));
    const float gateB = __builtin_amdgcn_rcpf(1.0f + __builtin_amdgcn_exp2f(-LOG2E * glB));
    const float finA  = fmaf(gateA, attA - gxA.y, gxA.y);
    const float finB  = fmaf(gateB, attB - gxB.y, gxB.y);
    QOT[pA*64 + c] = finA;                // coalesced full-line (N,C) stores
    pacc += finA;
    if (hasB) { QOT[pB*64 + c] = finB; pacc += finB; }
  }

  // pool reduce: 4 waves -> 64 lanes -> 64 device atomics
  alsA[t] = pacc;
  __syncthreads();
  if (t < 64) {
    float s = alsA[t] + alsA[64 + t] + alsA[128 + t] + alsA[192 + t];
    atomicAdd(&pool[b*64 + t], s);
  }
}

// ---------------------------------------------------------------------------
// Kernel 3: (N,C) -> (B,C,N) transpose through padded LDS (full-line reads
// AND writes). Block 0 additionally runs the GRU cell.
// ---------------------------------------------------------------------------
__global__ __launch_bounds__(256) void outpool_kernel(
    const float* __restrict__ OT, float* __restrict__ out,
    const float* __restrict__ pool, const float* __restrict__ prev,
    const float* __restrict__ W_ih, const float* __restrict__ W_hh,
    const float* __restrict__ b_ih, const float* __restrict__ b_hh,
    float* __restrict__ outmem)
{
  __shared__ __align__(16) float ls[64*65];
  __shared__ __align__(16) float mu[128];
  __shared__ float gi[384];
  __shared__ float gh[384];
  const int t  = threadIdx.x;
  const int bi = blockIdx.x;
  const int b  = bi / 216;
  const int n0 = (bi - b*216) * 64;
  #pragma unroll
  for (int i = 0; i < 16; ++i) {
    int u = i*256 + t;
    int pos = u >> 6, cc = u & 63;
    ls[cc*65 + pos] = OT[(size_t)(b*NPOS + n0 + pos)*64 + cc];  // coalesced read
  }
  if (bi == 0 && t < 128) mu[t] = pool[t] * (1.0f / (float)NPOS);
  __syncthreads();
  #pragma unroll
  for (int i = 0; i < 16; ++i) {
    int u = i*256 + t;
    int cc = u >> 6, j = u & 63;
    out[(size_t)(b*64 + cc)*NPOS + n0 + j] = ls[cc*65 + j];     // coalesced write
  }
  if (bi != 0) return;

  // ---- GRU cell (block 0 only) ----
  for (int r = t; r < 384; r += 256) {
    const int b2 = r / 192, j = r - b2*192;
    const float4* wi4 = (const float4*)(W_ih + (size_t)j*64);
    const float4* wh4 = (const float4*)(W_hh + (size_t)j*64);
    const float4* mu4 = (const float4*)(mu + b2*64);
    const float4* pv4 = (const float4*)(prev + b2*64);
    float sgi = b_ih[j], sgh = b_hh[j];
    #pragma unroll
    for (int k = 0; k < 16; ++k) {
      float4 wv = wi4[k], m4 = mu4[k];
      sgi = fmaf(wv.x, m4.x, sgi); sgi = fmaf(wv.y, m4.y, sgi);
      sgi = fmaf(wv.z, m4.z, sgi); sgi = fmaf(wv.w, m4.w, sgi);
      float4 hv = wh4[k], p4 = pv4[k];
      sgh = fmaf(hv.x, p4.x, sgh); sgh = fmaf(hv.y, p4.y, sgh);
      sgh = fmaf(hv.z, p4.z, sgh); sgh = fmaf(hv.w, p4.w, sgh);
    }
    gi[r] = sgi; gh[r] = sgh;
  }
  __syncthreads();
  if (t < 128) {
    const int b2 = t >> 6, cc = t & 63;
    float ir = gi[b2*192 + cc],       hr = gh[b2*192 + cc];
    float iz = gi[b2*192 + 64 + cc],  hz = gh[b2*192 + 64 + cc];
    float ii = gi[b2*192 + 128 + cc], hn = gh[b2*192 + 128 + cc];
    float rr = 1.0f / (1.0f + __builtin_amdgcn_exp2f(-LOG2E * (ir + hr)));
    float zz = 1.0f / (1.0f + __builtin_amdgcn_exp2f(-LOG2E * (iz + hz)));
    float ng = tanhf(ii + rr * hn);
    outmem[t] = (1.0f - zz) * ng + zz * prev[t];
  }
}

// ---------------------------------------------------------------------------
extern "C" void kernel_launch(void* const* d_in, const int* in_sizes, int n_in,
                              void* d_out, int out_size, void* d_ws, size_t ws_size,
                              hipStream_t stream) {
  const float* x    = (const float*)d_in[0];
  const float* prev = (const float*)d_in[1];
  const float* Wq   = (const float*)d_in[2];
  const float* bq   = (const float*)d_in[3];
  const float* Wk   = (const float*)d_in[4];
  const float* bk   = (const float*)d_in[5];
  const float* Wv   = (const float*)d_in[6];
  const float* bv   = (const float*)d_in[7];
  const float* memk = (const float*)d_in[8];
  const float* memv = (const float*)d_in[9];
  const float* Wg   = (const float*)d_in[10];
  const float* bg   = (const float*)d_in[11];
  const float* W_ih = (const float*)d_in[12];
  const float* W_hh = (const float*)d_in[13];
  const float* b_ih = (const float*)d_in[14];
  const float* b_hh = (const float*)d_in[15];

  float* out    = (float*)d_out;                 // (B,C,H,D,W)
  float* outmem = out + (size_t)BTCH*CDIM*NPOS;  // (B,C)

  const size_t SZ = (size_t)BTCH*NPOS*CDIM;      // 1769472
  float* wsf       = (float*)d_ws;
  float* Qb        = wsf;                        // also attn output (OT)
  unsigned int* KVp = (unsigned int*)(wsf + SZ); // bf16 K|V packed
  float* GXT       = wsf + 2*SZ;                 // float2 per element: 2*SZ
  float* pool      = wsf + 4*SZ;                 // 128 floats

  qkvg_kernel<<<BTCH*216, 256, 0, stream>>>(x, Wq, bq, Wk, bk, Wv, bv, Wg,
                                            Qb, KVp, GXT, pool);
  attn_kernel<<<BTCH*512, 256, 0, stream>>>(Qb, KVp, GXT,
                                            bk, bv, memk, memv, Wg, bg, pool);
  outpool_kernel<<<BTCH*216, 256, 0, stream>>>(Qb, out, pool, prev,
                                               W_ih, W_hh, b_ih, b_hh, outmem);
}